// Round 5
// baseline (174.936 us; speedup 1.0000x reference)
//
#include <hip/hip_runtime.h>
#include <stdint.h>

#define D_MODEL 1024
#define D_STATE 16
#define BB 4
#define TT 2048
#define MM (BB*TT)       /* 8192 rows */
#define NCH 64           /* time chunks */
#define CL (TT/NCH)      /* 32 steps per chunk */

typedef __attribute__((ext_vector_type(4))) float f32x4;
typedef __attribute__((ext_vector_type(8))) short short8;

__device__ __forceinline__ unsigned short f2bf(float f) {
  union { float f; uint32_t u; } v; v.f = f;
  uint32_t r = v.u + 0x7FFFu + ((v.u >> 16) & 1u);   // RNE
  return (unsigned short)(r >> 16);
}

__device__ __forceinline__ float softplusf(float v) {
  return v > 20.f ? v : log1pf(expf(v));
}

__device__ __forceinline__ f32x4 splat4(float s) {
  f32x4 r; r[0]=s; r[1]=s; r[2]=s; r[3]=s; return r;
}
__device__ __forceinline__ f32x4 exp2v4(f32x4 v) {
  f32x4 r;
  r[0]=__builtin_amdgcn_exp2f(v[0]);
  r[1]=__builtin_amdgcn_exp2f(v[1]);
  r[2]=__builtin_amdgcn_exp2f(v[2]);
  r[3]=__builtin_amdgcn_exp2f(v[3]);
  return r;
}

// ---------------- f32 -> bf16 conversion (float4 vectorized) ----------------
__global__ __launch_bounds__(256) void cvt_bf16_kernel(
    const float* __restrict__ in, unsigned short* __restrict__ out, int n4)
{
  const float4* in4 = (const float4*)in;
  ushort4* out4 = (ushort4*)out;
  int i = blockIdx.x * blockDim.x + threadIdx.x;
  const int stride = gridDim.x * blockDim.x;
  for (; i < n4; i += stride) {
    float4 v = in4[i];
    ushort4 o;
    o.x = f2bf(v.x); o.y = f2bf(v.y); o.z = f2bf(v.z); o.w = f2bf(v.w);
    out4[i] = o;
  }
}

// ---------------- precompute c2[e][s] = -(softplus(a_log)+1e-4)*log2e -------
__global__ __launch_bounds__(256) void prep_c2_kernel(
    const float* __restrict__ a_log, float* __restrict__ c2tab, int n)
{
  int i = blockIdx.x * 256 + threadIdx.x;
  if (i < n) {
    const float ap = softplusf(a_log[i]) + 1e-4f;
    c2tab[i] = -ap * 1.44269504088896f;
  }
}

// ---------------- bf16 GEMM, B^T layout: C[m][n] = sum_k A[m][k]*B[n][k] ----
// 128x128 tile, BK=32, 4 waves (2x2, each 64x64), double-buffered LDS.
// LDS holds FRAGMENT-ORDERED 1KB chunks: chunk s (byte s*1024), lane l <->
// element A[s*16 + (l&15)][(l>>4)*8 .. +7]. Staged via per-lane GLOBAL source
// addresses with wave-uniform LDS dest (HW adds lane*16), so compute-phase
// ds_read_b128 at chunkbase + lane*16 is conflict-free by construction.
__device__ __forceinline__ void stage_frag(
    const unsigned short* __restrict__ A, const unsigned short* __restrict__ Bm,
    unsigned short* Al, unsigned short* Bl,
    int bm, int bn, int k0, int K, int w, int l)
{
  const int r16 = l & 15;
  const int khb = (l >> 4) * 16;     // byte offset of this lane's 8 bf16 in k
  #pragma unroll
  for (int r = 0; r < 2; ++r) {
    const int s = w + r*4;           // chunk 0..7 (wave-uniform)
    const char* ga = (const char*)A  + ((size_t)(bm + s*16 + r16)*K + k0)*2 + khb;
    const char* gb = (const char*)Bm + ((size_t)(bn + s*16 + r16)*K + k0)*2 + khb;
    __builtin_amdgcn_global_load_lds(
        (const __attribute__((address_space(1))) void*)ga,
        (__attribute__((address_space(3))) void*)((char*)Al + s*1024), 16, 0, 0);
    __builtin_amdgcn_global_load_lds(
        (const __attribute__((address_space(1))) void*)gb,
        (__attribute__((address_space(3))) void*)((char*)Bl + s*1024), 16, 0, 0);
  }
}

template<bool SOFTPLUS>
__global__ __launch_bounds__(256, 4) void gemm_bt_kernel(
    const unsigned short* __restrict__ A,   // M x K bf16 (row-major)
    const unsigned short* __restrict__ Bm,  // N x K bf16 (row-major, i.e. B^T)
    const float* __restrict__ bias,         // N
    float* __restrict__ C,                  // M x N f32
    int M, int N, int K)
{
  __shared__ __align__(16) unsigned short Al[2][4096];  // 2 x 8KB (8 chunks)
  __shared__ __align__(16) unsigned short Bl[2][4096];
  const int tid  = threadIdx.x;
  const int lane = tid & 63;
  const int w    = tid >> 6;           // wave 0..3
  const int wr   = w >> 1, wc = w & 1; // 2x2 wave grid, 64x64 each
  const int r16  = lane & 15, kh = lane >> 4;

  // T1: bijective XCD chunk swizzle (nwg % 8 == 0)
  const int nwg   = gridDim.x;
  const int flat  = blockIdx.x;
  const int newid = (flat & 7) * (nwg >> 3) + (flat >> 3);
  const int bm    = (newid >> 3) * 128;
  const int bn    = (newid & 7) * 128;

  f32x4 acc[4][4] = {};

  const int NT = K >> 5;    // 32
  stage_frag(A, Bm, Al[0], Bl[0], bm, bn, 0, K, w, lane);

  for (int i = 0; i < NT; ++i) {
    if (i + 1 < NT) {
      stage_frag(A, Bm, Al[(i+1)&1], Bl[(i+1)&1], bm, bn, (i+1)*32, K, w, lane);
      asm volatile("s_waitcnt vmcnt(4)" ::: "memory");  // tile i's 4 loads done
    } else {
      asm volatile("s_waitcnt vmcnt(0)" ::: "memory");
    }
    __builtin_amdgcn_s_barrier();   // tile i visible to all waves

    const char* Ab = (const char*)Al[i & 1] + (wr*4)*1024 + lane*16;
    const char* Bb = (const char*)Bl[i & 1] + (wc*4)*1024 + lane*16;
    short8 af[4], bf[4];
    #pragma unroll
    for (int m = 0; m < 4; ++m) af[m] = *(const short8*)(Ab + m*1024);
    #pragma unroll
    for (int n = 0; n < 4; ++n) bf[n] = *(const short8*)(Bb + n*1024);
    #pragma unroll
    for (int m = 0; m < 4; ++m)
      #pragma unroll
      for (int n = 0; n < 4; ++n)
        acc[m][n] = __builtin_amdgcn_mfma_f32_16x16x32_bf16(af[m], bf[n], acc[m][n], 0, 0, 0);

    __builtin_amdgcn_s_barrier();   // reads of buf[i&1] done before overwrite
  }

  // epilogue: row = bm + wr*64 + m*16 + kh*4 + j ; col = bn + wc*64 + n*16 + r16
  #pragma unroll
  for (int n = 0; n < 4; ++n) {
    const int col = bn + wc*64 + n*16 + r16;
    const float bv = bias[col];
    #pragma unroll
    for (int m = 0; m < 4; ++m) {
      #pragma unroll
      for (int j = 0; j < 4; ++j) {
        const int row = bm + wr*64 + m*16 + kh*4 + j;
        float v = acc[m][n][j] + bv;
        if (SOFTPLUS) v = softplusf(v);
        C[(size_t)row*N + col] = v;
      }
    }
  }
}

// ---------------- scan pass 1: per-chunk local state L and sum(dt) ----------
__global__ __launch_bounds__(256) void scan_pass1_kernel(
    const float* __restrict__ x, const float* __restrict__ delta,
    const float* __restrict__ c2tab,
    float* __restrict__ Lc, float* __restrict__ dts_out)
{
  const int e  = blockIdx.x * 256 + threadIdx.x;
  const int b  = blockIdx.y >> 6;            // NCH = 64
  const int c  = blockIdx.y & (NCH-1);

  const f32x4* c2p = (const f32x4*)(c2tab + (size_t)e*D_STATE);
  const f32x4 c20=c2p[0], c21=c2p[1], c22=c2p[2], c23=c2p[3];

  f32x4 S0=splat4(0.f), S1=splat4(0.f), S2=splat4(0.f), S3=splat4(0.f);
  const size_t base = ((size_t)b*TT + (size_t)c*CL)*D_MODEL + e;
  const float* xp = x + base;
  const float* dp = delta + base;
  float dts = 0.f;
  #pragma unroll 4
  for (int t = 0; t < CL; ++t) {
    const float dt = dp[(size_t)t*D_MODEL];
    const float xv = xp[(size_t)t*D_MODEL];
    dts += dt;
    const f32x4 u4 = splat4(dt*xv);
    const f32x4 d4 = splat4(dt);
    S0 = exp2v4(c20*d4)*S0 + u4;
    S1 = exp2v4(c21*d4)*S1 + u4;
    S2 = exp2v4(c22*d4)*S2 + u4;
    S3 = exp2v4(c23*d4)*S3 + u4;
  }
  const size_t ci = ((size_t)c*BB + b)*D_MODEL + e;
  dts_out[ci] = dts;
  f32x4* Lp = (f32x4*)&Lc[ci*D_STATE];
  Lp[0]=S0; Lp[1]=S1; Lp[2]=S2; Lp[3]=S3;
}

// ---------------- scan pass 2: in-place exclusive scan over chunks ----------
__global__ __launch_bounds__(256) void scan_pass2_kernel(
    const float* __restrict__ c2tab,
    float* __restrict__ Lc, const float* __restrict__ dts)
{
  const int tid = blockIdx.x * 256 + threadIdx.x;  // < 65536
  const int e = (tid >> 4) & (D_MODEL - 1);
  const int b = tid >> 14;
  const float c2 = c2tab[tid & (D_MODEL*D_STATE - 1)];  // e*16 + s
  float S = 0.f;
  for (int c = 0; c < NCH; ++c) {
    const size_t ce  = ((size_t)c*BB + b)*D_MODEL + e;
    const size_t idx = ce*D_STATE + (tid & 15);
    const float L  = Lc[idx];
    const float Ac = __builtin_amdgcn_exp2f(c2 * dts[ce]);
    Lc[idx] = S;                 // exclusive prefix (chunk initial state)
    S = Ac*S + L;
  }
}

// ---------------- scan pass 3: recompute with carry-in, emit y (bf16) -------
__global__ __launch_bounds__(256) void scan_pass3_kernel(
    const float* __restrict__ x, const float* __restrict__ delta,
    const float* __restrict__ c2tab, const float* __restrict__ b_param,
    const float* __restrict__ Lc, unsigned short* __restrict__ yb)
{
  const int e  = blockIdx.x * 256 + threadIdx.x;
  const int b  = blockIdx.y >> 6;
  const int c  = blockIdx.y & (NCH-1);

  const f32x4* c2p = (const f32x4*)(c2tab + (size_t)e*D_STATE);
  const f32x4 c20=c2p[0], c21=c2p[1], c22=c2p[2], c23=c2p[3];
  const f32x4* bpp = (const f32x4*)(b_param + (size_t)e*D_STATE);
  const f32x4 bp0=bpp[0], bp1=bpp[1], bp2=bpp[2], bp3=bpp[3];

  const size_t ci = ((size_t)c*BB + b)*D_MODEL + e;
  const f32x4* Lp = (const f32x4*)&Lc[ci*D_STATE];
  f32x4 S0=Lp[0], S1=Lp[1], S2=Lp[2], S3=Lp[3];

  const size_t base = ((size_t)b*TT + (size_t)c*CL)*D_MODEL + e;
  const float* xp = x + base;
  const float* dp = delta + base;
  #pragma unroll 4
  for (int t = 0; t < CL; ++t) {
    const float dt = dp[(size_t)t*D_MODEL];
    const float xv = xp[(size_t)t*D_MODEL];
    const f32x4 u4 = splat4(dt*xv);
    const f32x4 d4 = splat4(dt);
    S0 = exp2v4(c20*d4)*S0 + u4;
    S1 = exp2v4(c21*d4)*S1 + u4;
    S2 = exp2v4(c22*d4)*S2 + u4;
    S3 = exp2v4(c23*d4)*S3 + u4;
    const f32x4 yv = bp0*S0 + bp1*S1 + bp2*S2 + bp3*S3;
    const float y = (yv[0]+yv[1]) + (yv[2]+yv[3]);
    yb[base + (size_t)t*D_MODEL] = f2bf(y);
  }
}

// ---------------------------------------------------------------------------
extern "C" void kernel_launch(void* const* d_in, const int* in_sizes, int n_in,
                              void* d_out, int out_size, void* d_ws, size_t ws_size,
                              hipStream_t stream)
{
  (void)in_sizes; (void)n_in; (void)out_size; (void)ws_size;
  const float* x       = (const float*)d_in[0];
  const float* Wd      = (const float*)d_in[1];
  const float* bd      = (const float*)d_in[2];
  const float* a_log   = (const float*)d_in[3];
  const float* b_param = (const float*)d_in[4];
  const float* Wo      = (const float*)d_in[5];
  const float* bo      = (const float*)d_in[6];
  float* out = (float*)d_out;

  // workspace layout (69 MB). Lc/dts alias xb: xb is dead after GEMM1.
  char* ws = (char*)d_ws;
  unsigned short* xb  = (unsigned short*)(ws);              // 16 MB (bf16 x)
  float*          Lc  = (float*)(ws);                       // 16 MB (aliases xb)
  float*          dts = (float*)(ws + 16777216);            //  1 MB
  unsigned short* wdb = (unsigned short*)(ws + 17825792);   //  2 MB
  unsigned short* wob = (unsigned short*)(ws + 19922944);   //  2 MB
  float*          delta = (float*)(ws + 22020096);          // 32 MB
  unsigned short* yb  = (unsigned short*)(ws + 55574528);   // 16 MB

  // c2 table (64 KB) lives at the head of d_out; every scan pass reads it
  // before GEMM2 fully overwrites d_out at the end. Deterministic each call.
  float* c2tab = (float*)d_out;

  prep_c2_kernel<<<(D_MODEL*D_STATE)/256, 256, 0, stream>>>(
      a_log, c2tab, D_MODEL*D_STATE);

  cvt_bf16_kernel<<<1024, 256, 0, stream>>>(x,  xb,  (MM*D_MODEL)/4);
  cvt_bf16_kernel<<<512,  256, 0, stream>>>(Wd, wdb, (D_MODEL*D_MODEL)/4);
  cvt_bf16_kernel<<<512,  256, 0, stream>>>(Wo, wob, (D_MODEL*D_MODEL)/4);

  gemm_bt_kernel<true><<<dim3((MM/128)*(D_MODEL/128)), 256, 0, stream>>>(
      xb, wdb, bd, delta, MM, D_MODEL, D_MODEL);

  scan_pass1_kernel<<<dim3(D_MODEL/256, BB*NCH), 256, 0, stream>>>(
      x, delta, c2tab, Lc, dts);
  scan_pass2_kernel<<<(BB*D_MODEL*D_STATE)/256, 256, 0, stream>>>(
      c2tab, Lc, dts);
  scan_pass3_kernel<<<dim3(D_MODEL/256, BB*NCH), 256, 0, stream>>>(
      x, delta, c2tab, b_param, Lc, yb);

  gemm_bt_kernel<false><<<dim3((MM/128)*(D_MODEL/128)), 256, 0, stream>>>(
      yb, wob, bo, out, MM, D_MODEL, D_MODEL);
}